// Round 11
// baseline (1039.100 us; speedup 1.0000x reference)
//
#include <hip/hip_runtime.h>
#include <float.h>

#define NTOK   2048
#define VOCAB  32000
#define DIM    512
#define NCHUNK 50
#define NT16   2000               // 16-col vocab tiles
#define TPC    40                 // tiles per chunk
#define ROWSB  64                 // rows per block (4 waves x 16 rows)
#define NRB    (NTOK / ROWSB)     // 32
#define TILE_BYTES 8192           // 16 cols x 512 k x 1B fp8, fragment-linear

typedef __attribute__((ext_vector_type(4))) float f32x4;
typedef unsigned int u32;
typedef long long i64;

// pack 8 consecutive fp32 (k..k+7) into 8 fp8-e4m3 bytes (k-order = byte order)
__device__ __forceinline__ i64 pack_fp8x8(f32x4 x0, f32x4 x1) {
    int lo = __builtin_amdgcn_cvt_pk_fp8_f32(x0.x, x0.y, 0, false);
    lo = __builtin_amdgcn_cvt_pk_fp8_f32(x0.z, x0.w, lo, true);
    int hi = __builtin_amdgcn_cvt_pk_fp8_f32(x1.x, x1.y, 0, false);
    hi = __builtin_amdgcn_cvt_pk_fp8_f32(x1.z, x1.w, hi, true);
    return (i64)(((unsigned long long)(u32)hi << 32) | (u32)lo);
}

__device__ __forceinline__ void async_copy16(void* lds, const void* g) {
    __builtin_amdgcn_global_load_lds(
        (const __attribute__((address_space(1))) u32*)(const u32*)g,
        (__attribute__((address_space(3))) u32*)(u32*)lds, 16, 0, 0);
}

__global__ void init_out(float* out) {
    if (threadIdx.x < 2) out[threadIdx.x] = 0.f;
}

// ---- precast: emb fp32 -> fp8 FRAGMENT-LINEAR 16-col-tile image + e2 ----
// i64 at tile*8192 + ks*512 + il*8 holds emb[v0+(il&15)][ks*32+(il>>4)*8+j].
__global__ __launch_bounds__(256) void precast_kernel(
    const float* __restrict__ emb, char* __restrict__ Bbf, float* __restrict__ e2) {
    const int tile = blockIdx.x;
    const int t = threadIdx.x, w = t >> 6, l = t & 63;
    const int v0 = tile * 16;
    char* tbase = Bbf + (size_t)tile * TILE_BYTES;
    #pragma unroll
    for (int it = 0; it < 4; ++it) {
        const int v = it * 4 + w;
        const float* src = emb + (size_t)(v0 + v) * DIM + l * 8;
        f32x4 x0 = *(const f32x4*)src;
        f32x4 x1 = *(const f32x4*)(src + 4);
        float sq = x0.x*x0.x + x0.y*x0.y + x0.z*x0.z + x0.w*x0.w
                 + x1.x*x1.x + x1.y*x1.y + x1.z*x1.z + x1.w*x1.w;
        #pragma unroll
        for (int m = 1; m < 64; m <<= 1) sq += __shfl_xor(sq, m);
        if (l == 0) e2[v0 + v] = sq;
        *(i64*)(tbase + (l >> 2) * 512 + ((l & 3) * 16 + v) * 8) = pack_fp8x8(x0, x1);
    }
}

// e2-only fallback
__global__ __launch_bounds__(256) void e2_kernel(const float* __restrict__ emb,
                                                 float* __restrict__ e2) {
    int gid = blockIdx.x * 256 + threadIdx.x;
    int wid = gid >> 6, l = gid & 63;
    if (wid >= VOCAB) return;
    const float* row = emb + (size_t)wid * DIM + l * 8;
    f32x4 a = *(const f32x4*)row;
    f32x4 b = *(const f32x4*)(row + 4);
    float s = a.x*a.x + a.y*a.y + a.z*a.z + a.w*a.w
            + b.x*b.x + b.y*b.y + b.z*b.z + b.w*b.w;
    #pragma unroll
    for (int m = 1; m < 64; m <<= 1) s += __shfl_xor(s, m);
    if (l == 0) e2[wid] = s;
}

// ---- common ablation body: r6-scheme (2 buffers, 2 barriers, counted vmcnt),
// q + e2 via global_load_lds so NO global loads remain in the steady loop ----
template<bool B_ON, bool Q_ON, bool EXP_ON, int REP>
__device__ __forceinline__ void fused_body(
    const float* __restrict__ pred_ll, const int* __restrict__ target,
    const char* __restrict__ Bbf, const float* __restrict__ e2g,
    float* __restrict__ outp) {

    const int rb = blockIdx.x;
    const int ch = blockIdx.y;
    const int t  = threadIdx.x;
    const int w  = t >> 6;                // 0..3
    const int l  = t & 63;
    const int l15 = l & 15;
    const int lg  = l >> 4;               // 0..3

    __shared__ __align__(16) char  ldsB[2][TILE_BYTES];  // 16 KB
    __shared__ __align__(16) float ldsQ[2][64 * 16];     // 8 KB
    __shared__ __align__(16) float e2l[TPC * 16];        // 2.56 KB

    const int t0 = ch * TPC, t1 = t0 + TPC;
    const int rowblk = rb * ROWSB;
    const int rowbase = rowblk + w * 16;

    i64 afrag[16];
    if constexpr (B_ON) {
        const int grow = target[rowbase + l15];
        const char* ab = Bbf + (size_t)(grow >> 4) * TILE_BYTES
                       + ((l & 48) + (grow & 15)) * 8;
        #pragma unroll
        for (int ks = 0; ks < 16; ++ks)
            afrag[ks] = *(const i64*)(ab + ks * 512);
    }
    float g2[4];
    #pragma unroll
    for (int r = 0; r < 4; ++r) g2[r] = e2g[target[rowbase + lg * 4 + r]];

    float s_[4] = {0.f, 0.f, 0.f, 0.f};
    float ac_[4] = {0.f, 0.f, 0.f, 0.f};

    constexpr int NG = (B_ON ? 2 : 0) + (Q_ON ? 1 : 0);

    auto stage = [&](int buf, int g) {
        if constexpr (B_ON) {
            const char* src = Bbf + (size_t)g * TILE_BYTES;
            async_copy16(ldsB[buf] + t * 16, src + t * 16);
            async_copy16(ldsB[buf] + 4096 + t * 16, src + 4096 + t * 16);
        }
        if constexpr (Q_ON) {
            const float* srcQ = pred_ll + (size_t)(rowblk + (t >> 2)) * VOCAB
                              + g * 16 + (t & 3) * 4;
            async_copy16((char*)&ldsQ[buf][0] + t * 16, srcQ);
        }
    };

    // e2 for the whole chunk, once (oldest in vmcnt queue; retired by 1st wait)
    if (t < TPC * 4) async_copy16(e2l + t * 4, e2g + t0 * 16 + t * 4);

    #pragma unroll 1
    for (int rep = 0; rep < REP; ++rep) {
        stage(0, t0);
        int cur = 0;
        #pragma unroll 1
        for (int g = t0; g < t1; ++g) {
            if (g + 1 < t1) {
                stage(cur ^ 1, g + 1);
                asm volatile("s_waitcnt vmcnt(%0)" :: "i"(NG) : "memory");
            } else {
                asm volatile("s_waitcnt vmcnt(0)" ::: "memory");
            }
            __builtin_amdgcn_s_barrier();

            f32x4 acc;
            if constexpr (B_ON) {
                acc = (f32x4){0.f, 0.f, 0.f, 0.f};
                const char* lb = ldsB[cur];
                #pragma unroll
                for (int ks = 0; ks < 16; ++ks) {
                    const i64 bb = *(const i64*)(lb + ks * 512 + l * 8);
                    acc = __builtin_amdgcn_mfma_f32_16x16x32_fp8_fp8(afrag[ks], bb, acc, 0, 0, 0);
                }
            } else {
                const float base = 0.001f * (float)l;
                acc = (f32x4){base, base + 0.01f, base + 0.02f, base + 0.03f};
            }

            const float e2v = e2l[(g - t0) * 16 + l15];
            #pragma unroll
            for (int r = 0; r < 4; ++r) {
                float q;
                if constexpr (Q_ON)
                    q = ldsQ[cur][(w * 16 + lg * 4 + r) * 16 + l15];
                else
                    q = 1.0f;
                float d2 = fmaxf(fmaf(-2.f, acc[r], g2[r] + e2v), 1e-12f);
                if constexpr (EXP_ON) {
                    const float e = __expf(-sqrtf(d2));
                    s_[r] += e;
                    ac_[r] = fmaf(e, -q, ac_[r]);
                } else {
                    s_[r] += d2;                       // keeps acc live
                    ac_[r] = fmaf(d2, -q, ac_[r]);     // keeps q live
                }
            }

            asm volatile("" ::: "memory");     // pin LDS reads before overwrite
            __builtin_amdgcn_s_barrier();
            cur ^= 1;
        }
    }

    #pragma unroll
    for (int r = 0; r < 4; ++r) {
        float sv = s_[r], av = ac_[r];
        #pragma unroll
        for (int m = 1; m < 16; m <<= 1) {
            sv += __shfl_xor(sv, m);
            av += __shfl_xor(av, m);
        }
        if (l15 == 0) {
            const int rg = rowbase + lg * 4 + r;
            float* pp = outp + ((size_t)rg * NCHUNK + ch) * 2;
            pp[0] = sv; pp[1] = av;
        }
    }
}

#define ABL_ARGS const float* __restrict__ pred_ll, const int* __restrict__ target, \
                 const char* __restrict__ Bbf, const float* __restrict__ e2g,       \
                 float* __restrict__ outp

__global__ __launch_bounds__(256, 6) void fused_full(ABL_ARGS) {
    fused_body<true,  true,  true,  1>(pred_ll, target, Bbf, e2g, outp);
}
__global__ __launch_bounds__(256, 6) void abl_noQ(ABL_ARGS) {
    fused_body<true,  false, true,  4>(pred_ll, target, Bbf, e2g, outp);
}
__global__ __launch_bounds__(256, 6) void abl_noB(ABL_ARGS) {
    fused_body<false, true,  true,  4>(pred_ll, target, Bbf, e2g, outp);
}
__global__ __launch_bounds__(256, 6) void abl_noE(ABL_ARGS) {
    fused_body<true,  true,  false, 4>(pred_ll, target, Bbf, e2g, outp);
}

// correctness fallback if ws can't hold the fp8 image (never taken so far)
__global__ __launch_bounds__(256) void fused_fallback(
    const float* __restrict__ pred_ll, const int* __restrict__ target,
    const float* __restrict__ emb, const float* __restrict__ e2g,
    float* __restrict__ partials) {
    const int rb = blockIdx.x, ch = blockIdx.y;
    const int t = threadIdx.x, w = t >> 6, l = t & 63, l15 = l & 15, lg = l >> 4;
    __shared__ char ldsB[TILE_BYTES];
    const int t0 = ch * TPC, t1 = t0 + TPC;
    const int rowbase = rb * ROWSB + w * 16;
    i64 afrag[16];
    {
        const int grow = target[rowbase + l15];
        const float* gsrc = emb + (size_t)grow * DIM;
        #pragma unroll
        for (int ks = 0; ks < 16; ++ks) {
            const int k0 = ks * 32 + ((l >> 4) << 3);
            afrag[ks] = pack_fp8x8(*(const f32x4*)(gsrc + k0),
                                   *(const f32x4*)(gsrc + k0 + 4));
        }
    }
    float g2[4];
    #pragma unroll
    for (int r = 0; r < 4; ++r) g2[r] = e2g[target[rowbase + lg * 4 + r]];
    float s_[4] = {0,0,0,0}, ac_[4] = {0,0,0,0};
    for (int g = t0; g < t1; ++g) {
        __syncthreads();
        #pragma unroll
        for (int it = 0; it < 4; ++it) {
            const int slot = it * 256 + t, ks = slot >> 6, il = slot & 63;
            const int v = il & 15, k0 = ks * 32 + ((il >> 4) << 3);
            const float* src = emb + (size_t)(g * 16 + v) * DIM + k0;
            *(i64*)(ldsB + ks * 512 + il * 8) =
                pack_fp8x8(*(const f32x4*)src, *(const f32x4*)(src + 4));
        }
        __syncthreads();
        f32x4 acc = {0.f, 0.f, 0.f, 0.f};
        #pragma unroll
        for (int ks = 0; ks < 16; ++ks) {
            const i64 bb = *(const i64*)(ldsB + ks * 512 + l * 8);
            acc = __builtin_amdgcn_mfma_f32_16x16x32_fp8_fp8(afrag[ks], bb, acc, 0, 0, 0);
        }
        const float e2v = e2g[g * 16 + l15];
        #pragma unroll
        for (int r = 0; r < 4; ++r) {
            const float q = pred_ll[(size_t)(rowbase + lg * 4 + r) * VOCAB + g * 16 + l15];
            float d2 = fmaxf(fmaf(-2.f, acc[r], g2[r] + e2v), 1e-12f);
            const float e = __expf(-sqrtf(d2));
            s_[r] += e;
            ac_[r] = fmaf(e, -q, ac_[r]);
        }
    }
    #pragma unroll
    for (int r = 0; r < 4; ++r) {
        float sv = s_[r], av = ac_[r];
        #pragma unroll
        for (int m = 1; m < 16; m <<= 1) { sv += __shfl_xor(sv, m); av += __shfl_xor(av, m); }
        if (l15 == 0) {
            const int rg = rowbase + lg * 4 + r;
            float* pp = partials + ((size_t)rg * NCHUNK + ch) * 2;
            pp[0] = sv; pp[1] = av;
        }
    }
}

__global__ __launch_bounds__(256) void reduce_kernel(
    const float* __restrict__ pred_ll, const int* __restrict__ target,
    const float* __restrict__ partials, float* __restrict__ out) {
    const int row = blockIdx.x * 256 + threadIdx.x;
    float loss = 0.f, nll = 0.f;
    if (row < NTOK) {
        const int tg = target[row];
        const float mask = (tg != 0) ? 1.f : 0.f;
        const float* pp = partials + (size_t)row * NCHUNK * 2;
        float S = 0.f, A = 0.f;
        #pragma unroll 5
        for (int c = 0; c < NCHUNK; ++c) { S += pp[c * 2]; A += pp[c * 2 + 1]; }
        loss = mask * (A / S);
        nll  = mask * (-pred_ll[(size_t)row * VOCAB + tg]);
    }
    #pragma unroll
    for (int o = 32; o > 0; o >>= 1) {
        loss += __shfl_xor(loss, o);
        nll  += __shfl_xor(nll, o);
    }
    if ((threadIdx.x & 63) == 0) {
        atomicAdd(&out[0], loss);
        atomicAdd(&out[1], nll);
    }
}

extern "C" void kernel_launch(void* const* d_in, const int* in_sizes, int n_in,
                              void* d_out, int out_size, void* d_ws, size_t ws_size,
                              hipStream_t stream) {
    const float* pred_ll = (const float*)d_in[0];
    const int*   target  = (const int*)d_in[1];
    const float* emb     = (const float*)d_in[2];
    float* out = (float*)d_out;

    // ws layout: [e2: VOCAB f32][partials: NTOK*NCHUNK*2 f32][fp8 image 16MB]
    float* e2       = (float*)d_ws;
    float* partials = e2 + VOCAB;
    const size_t base = (size_t)VOCAB * 4 + (size_t)NTOK * NCHUNK * 2 * 4;
    char* Bbf       = (char*)d_ws + base;
    const size_t need = base + (size_t)NT16 * TILE_BYTES;
    const bool precast = (ws_size >= need);

    hipLaunchKernelGGL(init_out, dim3(1), dim3(64), 0, stream, out);
    if (precast) {
        hipLaunchKernelGGL(precast_kernel, dim3(NT16), dim3(256), 0, stream, emb, Bbf, e2);
        // ablation probes first (scratch results overwritten by fused_full)
        hipLaunchKernelGGL(abl_noQ, dim3(NRB, NCHUNK), dim3(256), 0, stream,
                           pred_ll, target, Bbf, e2, partials);
        hipLaunchKernelGGL(abl_noB, dim3(NRB, NCHUNK), dim3(256), 0, stream,
                           pred_ll, target, Bbf, e2, partials);
        hipLaunchKernelGGL(abl_noE, dim3(NRB, NCHUNK), dim3(256), 0, stream,
                           pred_ll, target, Bbf, e2, partials);
        // the real pass (overwrites every partials slot)
        hipLaunchKernelGGL(fused_full, dim3(NRB, NCHUNK), dim3(256), 0, stream,
                           pred_ll, target, Bbf, e2, partials);
    } else {
        hipLaunchKernelGGL(e2_kernel, dim3(VOCAB * 64 / 256), dim3(256), 0, stream, emb, e2);
        hipLaunchKernelGGL(fused_fallback, dim3(NRB, NCHUNK), dim3(256), 0, stream,
                           pred_ll, target, emb, e2, partials);
    }
    hipLaunchKernelGGL(reduce_kernel, dim3(NTOK / 256), dim3(256), 0, stream,
                       pred_ll, target, partials, out);
}

// Round 12
// 169.183 us; speedup vs baseline: 6.1419x; 6.1419x over previous
//
#include <hip/hip_runtime.h>
#include <float.h>

#define NTOK   2048
#define VOCAB  32000
#define DIM    512
#define NCHUNK 50
#define NT16   2000               // 16-col vocab tiles
#define TPC    40                 // tiles per chunk
#define ROWSB  128                // rows per block (8 waves x 16 rows)
#define NRB    (NTOK / ROWSB)     // 16
#define TILE_BYTES 8192           // 16 cols x 512 k x 1B fp8, fragment-linear

typedef __attribute__((ext_vector_type(4))) float f32x4;
typedef unsigned int u32;
typedef long long i64;

__device__ __forceinline__ float fast_sqrt(float x) {
#if __has_builtin(__builtin_amdgcn_sqrtf)
    return __builtin_amdgcn_sqrtf(x);        // v_sqrt_f32, 1 instr
#else
    return sqrtf(x);
#endif
}
__device__ __forceinline__ float fast_exp2(float x) {
#if __has_builtin(__builtin_amdgcn_exp2f)
    return __builtin_amdgcn_exp2f(x);        // v_exp_f32, 1 instr
#else
    return __expf(x * 0.69314718056f);
#endif
}

// pack 8 consecutive fp32 (k..k+7) into 8 fp8-e4m3 bytes (k-order = byte order)
__device__ __forceinline__ i64 pack_fp8x8(f32x4 x0, f32x4 x1) {
    int lo = __builtin_amdgcn_cvt_pk_fp8_f32(x0.x, x0.y, 0, false);
    lo = __builtin_amdgcn_cvt_pk_fp8_f32(x0.z, x0.w, lo, true);
    int hi = __builtin_amdgcn_cvt_pk_fp8_f32(x1.x, x1.y, 0, false);
    hi = __builtin_amdgcn_cvt_pk_fp8_f32(x1.z, x1.w, hi, true);
    return (i64)(((unsigned long long)(u32)hi << 32) | (u32)lo);
}

__device__ __forceinline__ void async_copy16(void* lds, const void* g) {
    __builtin_amdgcn_global_load_lds(
        (const __attribute__((address_space(1))) u32*)(const u32*)g,
        (__attribute__((address_space(3))) u32*)(u32*)lds, 16, 0, 0);
}

__global__ void init_out(float* out) {
    if (threadIdx.x < 2) out[threadIdx.x] = 0.f;
}

// ---- precast: emb fp32 -> fp8 FRAGMENT-LINEAR 16-col-tile image + e2 ----
// i64 at tile*8192 + ks*512 + il*8 holds emb[v0+(il&15)][ks*32+(il>>4)*8+j].
__global__ __launch_bounds__(256) void precast_kernel(
    const float* __restrict__ emb, char* __restrict__ Bbf, float* __restrict__ e2) {
    const int tile = blockIdx.x;
    const int t = threadIdx.x, w = t >> 6, l = t & 63;
    const int v0 = tile * 16;
    char* tbase = Bbf + (size_t)tile * TILE_BYTES;
    #pragma unroll
    for (int it = 0; it < 4; ++it) {
        const int v = it * 4 + w;
        const float* src = emb + (size_t)(v0 + v) * DIM + l * 8;
        f32x4 x0 = *(const f32x4*)src;
        f32x4 x1 = *(const f32x4*)(src + 4);
        float sq = x0.x*x0.x + x0.y*x0.y + x0.z*x0.z + x0.w*x0.w
                 + x1.x*x1.x + x1.y*x1.y + x1.z*x1.z + x1.w*x1.w;
        #pragma unroll
        for (int m = 1; m < 64; m <<= 1) sq += __shfl_xor(sq, m);
        if (l == 0) e2[v0 + v] = sq;
        *(i64*)(tbase + (l >> 2) * 512 + ((l & 3) * 16 + v) * 8) = pack_fp8x8(x0, x1);
    }
}

// e2-only fallback
__global__ __launch_bounds__(256) void e2_kernel(const float* __restrict__ emb,
                                                 float* __restrict__ e2) {
    int gid = blockIdx.x * 256 + threadIdx.x;
    int wid = gid >> 6, l = gid & 63;
    if (wid >= VOCAB) return;
    const float* row = emb + (size_t)wid * DIM + l * 8;
    f32x4 a = *(const f32x4*)row;
    f32x4 b = *(const f32x4*)(row + 4);
    float s = a.x*a.x + a.y*a.y + a.z*a.z + a.w*a.w
            + b.x*b.x + b.y*b.y + b.z*b.z + b.w*b.w;
    #pragma unroll
    for (int m = 1; m < 64; m <<= 1) s += __shfl_xor(s, m);
    if (l == 0) e2[wid] = s;
}

// ---- fused: fp8 MFMA, 8 waves x 16 rows = 128 rows/block (B redundancy x16);
// r11 2-buffer/2-barrier body; q+e2 via global_load_lds; 1-instr sqrt/exp ----
__global__ __launch_bounds__(512, 6) void fused_full(
    const float* __restrict__ pred_ll, const int* __restrict__ target,
    const char* __restrict__ Bbf, const float* __restrict__ e2g,
    float* __restrict__ partials /* [NTOK][NCHUNK][2] */) {

    const int rb = blockIdx.x;
    const int ch = blockIdx.y;
    const int t  = threadIdx.x;
    const int w  = t >> 6;                // 0..7
    const int l  = t & 63;
    const int l15 = l & 15;
    const int lg  = l >> 4;               // 0..3

    __shared__ __align__(16) char  ldsB[2][TILE_BYTES];   // 16 KB
    __shared__ __align__(16) float ldsQ[2][ROWSB * 16];   // 16 KB
    __shared__ __align__(16) float e2l[TPC * 16];         // 2.56 KB

    const int t0 = ch * TPC, t1 = t0 + TPC;
    const int rowblk = rb * ROWSB;
    const int rowbase = rowblk + w * 16;

    // A fragments: 16 gold rows per wave, fp8, 32 regs
    i64 afrag[16];
    {
        const int grow = target[rowbase + l15];
        const char* ab = Bbf + (size_t)(grow >> 4) * TILE_BYTES
                       + ((l & 48) + (grow & 15)) * 8;
        #pragma unroll
        for (int ks = 0; ks < 16; ++ks)
            afrag[ks] = *(const i64*)(ab + ks * 512);
    }
    float g2[4];
    #pragma unroll
    for (int r = 0; r < 4; ++r) g2[r] = e2g[target[rowbase + lg * 4 + r]];

    float s_[4] = {0.f, 0.f, 0.f, 0.f};
    float ac_[4] = {0.f, 0.f, 0.f, 0.f};

    // stage tile g into buffer buf: B (8KB, 1 gll/thread) + q (8KB, 1 gll)
    auto stage = [&](int buf, int g) {
        async_copy16(ldsB[buf] + t * 16, Bbf + (size_t)g * TILE_BYTES + t * 16);
        const float* srcQ = pred_ll + (size_t)(rowblk + (t >> 2)) * VOCAB
                          + g * 16 + (t & 3) * 4;
        async_copy16((char*)&ldsQ[buf][0] + t * 16, srcQ);
    };

    // e2 for the whole chunk, once (oldest in queue; retired by first wait)
    if (t < TPC * 4) async_copy16(e2l + t * 4, e2g + t0 * 16 + t * 4);

    stage(0, t0);
    int cur = 0;
    #pragma unroll 1
    for (int g = t0; g < t1; ++g) {
        if (g + 1 < t1) {
            stage(cur ^ 1, g + 1);
            asm volatile("s_waitcnt vmcnt(2)" ::: "memory");  // this body's B+q resident
        } else {
            asm volatile("s_waitcnt vmcnt(0)" ::: "memory");
        }
        __builtin_amdgcn_s_barrier();

        // MFMA: 16 rows x 16 cols, K=512, fp8
        f32x4 acc = {0.f, 0.f, 0.f, 0.f};
        const char* lb = ldsB[cur];
        #pragma unroll
        for (int ks = 0; ks < 16; ++ks) {
            const i64 bb = *(const i64*)(lb + ks * 512 + l * 8);
            acc = __builtin_amdgcn_mfma_f32_16x16x32_fp8_fp8(afrag[ks], bb, acc, 0, 0, 0);
        }

        // epilogue: dist -> exp(-dist), fixed max = 0 (exact: dist >= 0)
        const float e2v = e2l[(g - t0) * 16 + l15];
        #pragma unroll
        for (int r = 0; r < 4; ++r) {
            const float q = ldsQ[cur][(w * 16 + lg * 4 + r) * 16 + l15];
            const float d2 = fmaxf(fmaf(-2.f, acc[r], g2[r] + e2v), 1e-12f);
            const float e = fast_exp2(-1.44269504089f * fast_sqrt(d2));
            s_[r] += e;
            ac_[r] = fmaf(e, -q, ac_[r]);
        }

        asm volatile("" ::: "memory");     // pin LDS reads before overwrite
        __builtin_amdgcn_s_barrier();
        cur ^= 1;
    }

    // combine 16 col-slices within each 16-lane group
    #pragma unroll
    for (int r = 0; r < 4; ++r) {
        float sv = s_[r], av = ac_[r];
        #pragma unroll
        for (int m = 1; m < 16; m <<= 1) {
            sv += __shfl_xor(sv, m);
            av += __shfl_xor(av, m);
        }
        if (l15 == 0) {
            const int rg = rowbase + lg * 4 + r;
            float* pp = partials + ((size_t)rg * NCHUNK + ch) * 2;
            pp[0] = sv; pp[1] = av;
        }
    }
}

// correctness fallback if ws can't hold the fp8 image (never taken so far)
__global__ __launch_bounds__(512) void fused_fallback(
    const float* __restrict__ pred_ll, const int* __restrict__ target,
    const float* __restrict__ emb, const float* __restrict__ e2g,
    float* __restrict__ partials) {
    const int rb = blockIdx.x, ch = blockIdx.y;
    const int t = threadIdx.x, w = t >> 6, l = t & 63, l15 = l & 15, lg = l >> 4;
    __shared__ char ldsB[TILE_BYTES];
    const int t0 = ch * TPC, t1 = t0 + TPC;
    const int rowbase = rb * ROWSB + w * 16;
    i64 afrag[16];
    {
        const int grow = target[rowbase + l15];
        const float* gsrc = emb + (size_t)grow * DIM;
        #pragma unroll
        for (int ks = 0; ks < 16; ++ks) {
            const int k0 = ks * 32 + ((l >> 4) << 3);
            afrag[ks] = pack_fp8x8(*(const f32x4*)(gsrc + k0),
                                   *(const f32x4*)(gsrc + k0 + 4));
        }
    }
    float g2[4];
    #pragma unroll
    for (int r = 0; r < 4; ++r) g2[r] = e2g[target[rowbase + lg * 4 + r]];
    float s_[4] = {0,0,0,0}, ac_[4] = {0,0,0,0};
    for (int g = t0; g < t1; ++g) {
        __syncthreads();
        #pragma unroll
        for (int it = 0; it < 2; ++it) {
            const int slot = it * 512 + t, ks = slot >> 6, il = slot & 63;
            const int v = il & 15, k0 = ks * 32 + ((il >> 4) << 3);
            const float* src = emb + (size_t)(g * 16 + v) * DIM + k0;
            *(i64*)(ldsB + ks * 512 + il * 8) =
                pack_fp8x8(*(const f32x4*)src, *(const f32x4*)(src + 4));
        }
        __syncthreads();
        f32x4 acc = {0.f, 0.f, 0.f, 0.f};
        #pragma unroll
        for (int ks = 0; ks < 16; ++ks) {
            const i64 bb = *(const i64*)(ldsB + ks * 512 + l * 8);
            acc = __builtin_amdgcn_mfma_f32_16x16x32_fp8_fp8(afrag[ks], bb, acc, 0, 0, 0);
        }
        const float e2v = e2g[g * 16 + l15];
        #pragma unroll
        for (int r = 0; r < 4; ++r) {
            const float q = pred_ll[(size_t)(rowbase + lg * 4 + r) * VOCAB + g * 16 + l15];
            const float d2 = fmaxf(fmaf(-2.f, acc[r], g2[r] + e2v), 1e-12f);
            const float e = fast_exp2(-1.44269504089f * fast_sqrt(d2));
            s_[r] += e;
            ac_[r] = fmaf(e, -q, ac_[r]);
        }
    }
    #pragma unroll
    for (int r = 0; r < 4; ++r) {
        float sv = s_[r], av = ac_[r];
        #pragma unroll
        for (int m = 1; m < 16; m <<= 1) { sv += __shfl_xor(sv, m); av += __shfl_xor(av, m); }
        if (l15 == 0) {
            const int rg = rowbase + lg * 4 + r;
            float* pp = partials + ((size_t)rg * NCHUNK + ch) * 2;
            pp[0] = sv; pp[1] = av;
        }
    }
}

__global__ __launch_bounds__(256) void reduce_kernel(
    const float* __restrict__ pred_ll, const int* __restrict__ target,
    const float* __restrict__ partials, float* __restrict__ out) {
    const int row = blockIdx.x * 256 + threadIdx.x;
    float loss = 0.f, nll = 0.f;
    if (row < NTOK) {
        const int tg = target[row];
        const float mask = (tg != 0) ? 1.f : 0.f;
        const float* pp = partials + (size_t)row * NCHUNK * 2;
        float S = 0.f, A = 0.f;
        #pragma unroll 5
        for (int c = 0; c < NCHUNK; ++c) { S += pp[c * 2]; A += pp[c * 2 + 1]; }
        loss = mask * (A / S);
        nll  = mask * (-pred_ll[(size_t)row * VOCAB + tg]);
    }
    #pragma unroll
    for (int o = 32; o > 0; o >>= 1) {
        loss += __shfl_xor(loss, o);
        nll  += __shfl_xor(nll, o);
    }
    if ((threadIdx.x & 63) == 0) {
        atomicAdd(&out[0], loss);
        atomicAdd(&out[1], nll);
    }
}

extern "C" void kernel_launch(void* const* d_in, const int* in_sizes, int n_in,
                              void* d_out, int out_size, void* d_ws, size_t ws_size,
                              hipStream_t stream) {
    const float* pred_ll = (const float*)d_in[0];
    const int*   target  = (const int*)d_in[1];
    const float* emb     = (const float*)d_in[2];
    float* out = (float*)d_out;

    // ws layout: [e2: VOCAB f32][partials: NTOK*NCHUNK*2 f32][fp8 image 16MB]
    float* e2       = (float*)d_ws;
    float* partials = e2 + VOCAB;
    const size_t base = (size_t)VOCAB * 4 + (size_t)NTOK * NCHUNK * 2 * 4;
    char* Bbf       = (char*)d_ws + base;
    const size_t need = base + (size_t)NT16 * TILE_BYTES;
    const bool precast = (ws_size >= need);

    hipLaunchKernelGGL(init_out, dim3(1), dim3(64), 0, stream, out);
    if (precast) {
        hipLaunchKernelGGL(precast_kernel, dim3(NT16), dim3(256), 0, stream, emb, Bbf, e2);
        hipLaunchKernelGGL(fused_full, dim3(NRB, NCHUNK), dim3(512), 0, stream,
                           pred_ll, target, Bbf, e2, partials);
    } else {
        hipLaunchKernelGGL(e2_kernel, dim3(VOCAB * 64 / 256), dim3(256), 0, stream, emb, e2);
        hipLaunchKernelGGL(fused_fallback, dim3(NRB, NCHUNK), dim3(512), 0, stream,
                           pred_ll, target, emb, e2, partials);
    }
    hipLaunchKernelGGL(reduce_kernel, dim3(NTOK / 256), dim3(256), 0, stream,
                       pred_ll, target, partials, out);
}